// Round 24
// baseline (831952.930 us; speedup 1.0000x reference)
//
#include <hip/hip_runtime.h>

#define BLK 256
#define NIT 60

// ================= CSR build =================
__global__ void k_zeroi(int* p, int len) {
  int i = blockIdx.x * BLK + threadIdx.x;
  if (i < len) p[i] = 0;
}
__global__ void k_hist(const int* rows, int nnz, int* cnt) {
  int k = blockIdx.x * BLK + threadIdx.x;
  if (k < nnz) atomicAdd(&cnt[rows[k]], 1);
}
__global__ void k_scanA(const int* cnt, int* ptr, int* bsum, int vals, int len) {
  __shared__ int sm[BLK];
  int i = blockIdx.x * BLK + threadIdx.x;
  int v = (i < vals) ? cnt[i] : 0;
  sm[threadIdx.x] = v;
  __syncthreads();
  for (int off = 1; off < BLK; off <<= 1) {
    int t = (threadIdx.x >= off) ? sm[threadIdx.x - off] : 0;
    __syncthreads();
    sm[threadIdx.x] += t;
    __syncthreads();
  }
  if (i < len) ptr[i] = sm[threadIdx.x] - v;
  if (threadIdx.x == BLK - 1) bsum[blockIdx.x] = sm[BLK - 1];
}
__global__ void k_scanB(int* bsum, int nb) {
  __shared__ int sm[BLK];
  int t = threadIdx.x;
  int v = (t < nb) ? bsum[t] : 0;
  sm[t] = v;
  __syncthreads();
  for (int off = 1; off < BLK; off <<= 1) {
    int x = (t >= off) ? sm[t - off] : 0;
    __syncthreads();
    sm[t] += x;
    __syncthreads();
  }
  if (t < nb) bsum[t] = sm[t] - v;
}
__global__ void k_scanC(int* ptr, const int* bsum, int len) {
  int i = blockIdx.x * BLK + threadIdx.x;
  if (i < len) ptr[i] += bsum[blockIdx.x];
}
__global__ void k_place(const int* rows, int nnz, const int* ptr, int* cursor, int* perm) {
  int k = blockIdx.x * BLK + threadIdx.x;
  if (k >= nnz) return;
  int r = rows[k];
  int pos = ptr[r] + atomicAdd(&cursor[r], 1);
  perm[pos] = k;
}
__global__ void k_sortrows(int* perm, const int* ptr, int segs) {
  int r = blockIdx.x * BLK + threadIdx.x;
  if (r >= segs) return;
  int s0 = ptr[r], e0 = ptr[r + 1];
  for (int e = s0 + 1; e < e0; ++e) {
    int key = perm[e];
    int j = e - 1;
    while (j >= s0 && perm[j] > key) { perm[j + 1] = perm[j]; --j; }
    perm[j + 1] = key;
  }
}

// ===== np.add.at segment_sum replica: f32 products, f32 sequential ascending-k =====
__device__ __forceinline__ float gat32(int i, const int* ptr, const int* perm,
                                       const float* data, const int* idx, const float* u) {
  float acc = 0.f;
  int e1 = ptr[i + 1];
  for (int e = ptr[i]; e < e1; ++e) {
    int kk = perm[e];
    acc = __fadd_rn(acc, __fmul_rn(data[kk], u[idx[kk]]));
  }
  return acc;
}
__device__ __forceinline__ float gatMasked32(int i, const int* ptr, const int* perm,
                                             const float* data, const int* idx,
                                             const float* msk, const float* u2) {
  float acc = 0.f;
  int e1 = ptr[i + 1];
  for (int e = ptr[i]; e < e1; ++e) {
    int kk = perm[e];
    int c = idx[kk];
    acc = __fadd_rn(acc, __fmul_rn(data[kk], __fmul_rn(msk[c], u2[c])));
  }
  return acc;
}

// ===== Netlib reference-BLAS sdot replica (sdot.f, gfortran -ffp-contract=fast) =====
// Pure sequential ascending loop; 5-way unroll is order-preserving; each
// product+add contracts to a fused FMA: stemp = fma(x[i], y[i], stemp).
__global__ void k_sdot(const float* xx, const float* yy, int n, float* slot) {
  if (threadIdx.x != 0 || blockIdx.x != 0) return;
  float dot = 0.f;
  for (int i = 0; i < n; ++i) dot = fmaf(xx[i], yy[i], dot);
  *slot = dot;
}

// ================= setup =================
__global__ void k_prep(const float* y, const float* s, float* mask, float* pim,
                       float* scal, int m) {
  int i = blockIdx.x * BLK + threadIdx.x;
  if (i < m) {
    float v = __fsub_rn(y[i], s[i]);
    mask[i] = v > 0.f ? 1.f : 0.f;
    pim[i]  = v > 0.f ? v : 0.f;
  }
  if (blockIdx.x == 0) for (int jj = threadIdx.x; jj < 256; jj += BLK) scal[jj] = 0.f;
}
__global__ void k_Px(const int* ptrPr, const int* permPr, const float* Pd, const int* Pc,
                     const float* x, float* Px, int n) {
  int i = blockIdx.x * BLK + threadIdx.x;
  if (i < n) Px[i] = gat32(i, ptrPr, permPr, Pd, Pc, x);
}
// g = Px + PTx ; qg = q + g
__global__ void k_qg(const int* ptrPc, const int* permPc, const float* Pd, const int* Pr,
                     const float* q, const float* x, const float* Px, float* qg, int n) {
  int i = blockIdx.x * BLK + threadIdx.x;
  if (i >= n) return;
  float ptx = gat32(i, ptrPc, permPc, Pd, Pr, x);
  qg[i] = __fadd_rn(q[i], __fadd_rn(Px[i], ptx));
}
__global__ void k_dPx(const int* ptrPr, const int* permPr, const float* dPd, const int* Pc,
                      const float* x, float* dPx, int n) {
  int i = blockIdx.x * BLK + threadIdx.x;
  if (i < n) dPx[i] = gat32(i, ptrPr, permPr, dPd, Pc, x);
}
// rk[0:n] = -d1 ; d1 = (dPx + dA^T pim) + dq
__global__ void k_d1(const int* ptrAc, const int* permAc, const float* dAd, const int* Ar,
                     const float* dPx, const float* pim, const float* dq,
                     float* rk, float* zk, int n) {
  int i = blockIdx.x * BLK + threadIdx.x;
  if (i >= n) return;
  float t2 = gat32(i, ptrAc, permAc, dAd, Ar, pim);
  float d1 = __fadd_rn(__fadd_rn(dPx[i], t2), dq[i]);
  rk[i] = -d1;
  zk[i] = 0.f;
}
// rk[n:n+m] = -d2 ; d2 = (-dA x) + db
__global__ void k_d2(const int* ptrAr, const int* permAr, const float* dAd, const int* Ac,
                     const float* x, const float* db, float* rk, float* zk, int n, int m) {
  int j = blockIdx.x * BLK + threadIdx.x;
  if (j >= m) return;
  float t = gat32(j, ptrAr, permAr, dAd, Ac, x);
  rk[n + j] = -(__fadd_rn(-t, db[j]));
  zk[n + j] = 0.f;
}
// d3 = ((-s1) - s2) - s3 ; rk[N-1] = -d3 ; zk[N-1]=0
__global__ void k_rhs3(const float* scal, float* rk, float* zk, int N) {
  if (threadIdx.x != 0 || blockIdx.x != 0) return;
  float d3 = __fsub_rn(__fsub_rn(-scal[1], scal[2]), scal[3]);
  rk[N - 1] = -d3;
  zk[N - 1] = 0.f;
}

// ================= operators (all-f32 np semantics) =================
__global__ void k_w2(const float* u, const float* mask, float* w2, int n, int m) {
  int j = blockIdx.x * BLK + threadIdx.x;
  if (j < m) w2[j] = __fmul_rn(mask[j], u[n + j]);
}
// F n-rows: out = ((Pu1 + AT(mask u2)) + q u3 - u1) + u1
__global__ void k_Fn(const int* ptrPr, const int* permPr, const float* Pd, const int* Pc,
                     const int* ptrAc, const int* permAc, const float* Ad, const int* Ar,
                     const float* q, const float* mask,
                     const float* u, float* out, int n, int N) {
  int i = blockIdx.x * BLK + threadIdx.x;
  if (i >= n) return;
  float u3 = u[N - 1];
  float p = gat32(i, ptrPr, permPr, Pd, Pc, u);
  float a = gatMasked32(i, ptrAc, permAc, Ad, Ar, mask, u + n);
  float r1 = __fadd_rn(__fadd_rn(p, a), __fmul_rn(q[i], u3));
  float ui = u[i];
  out[i] = __fadd_rn(__fsub_rn(r1, ui), ui);
}
// F m-rows: out = (((-A u1) + b u3) - mask u2) + u2
__global__ void k_Fm(const int* ptrAr, const int* permAr, const float* Ad, const int* Ac,
                     const float* b, const float* mask,
                     const float* u, float* out, int n, int m, int N) {
  int j = blockIdx.x * BLK + threadIdx.x;
  if (j >= m) return;
  float u3 = u[N - 1];
  float au = gat32(j, ptrAr, permAr, Ad, Ac, u);
  float r2 = __fadd_rn(-au, __fmul_rn(b[j], u3));
  float u2 = u[n + j];
  float w2 = __fmul_rn(mask[j], u2);
  out[n + j] = __fadd_rn(__fsub_rn(r2, w2), u2);
}
// F scalar: r3 = ((-tA) - tB) + c*u3 ; out = (r3 - u3) + u3
__global__ void k_r3F(const float* scal, const float* u, float* out, int N) {
  if (threadIdx.x != 0 || blockIdx.x != 0) return;
  float u3 = u[N - 1];
  float r3 = __fadd_rn(__fsub_rn(-scal[1], scal[2]), __fmul_rn(scal[0], u3));
  out[N - 1] = __fadd_rn(__fsub_rn(r3, u3), u3);
}
// FT n-rows: out = (((PT u1 - AT u2) - qg u3) - u1) + u1
__global__ void k_FTn(const int* ptrPc, const int* permPc, const float* Pd, const int* Pr,
                      const int* ptrAc, const int* permAc, const float* Ad, const int* Ar,
                      const float* qg, const float* u, float* out, int n, int N) {
  int i = blockIdx.x * BLK + threadIdx.x;
  if (i >= n) return;
  float u3 = u[N - 1];
  float pt = gat32(i, ptrPc, permPc, Pd, Pr, u);
  float at = gat32(i, ptrAc, permAc, Ad, Ar, u + n);
  float r1 = __fsub_rn(__fsub_rn(pt, at), __fmul_rn(qg[i], u3));
  float ui = u[i];
  out[i] = __fadd_rn(__fsub_rn(r1, ui), ui);
}
// FT m-rows: z2 = (A u1) - b u3 ; out = (mask z2 - mask u2) + u2
__global__ void k_FTm(const int* ptrAr, const int* permAr, const float* Ad, const int* Ac,
                      const float* b, const float* mask,
                      const float* u, float* out, int n, int m, int N) {
  int j = blockIdx.x * BLK + threadIdx.x;
  if (j >= m) return;
  float u3 = u[N - 1];
  float au = gat32(j, ptrAr, permAr, Ad, Ac, u);
  float z2 = __fsub_rn(au, __fmul_rn(b[j], u3));
  float u2 = u[n + j];
  float mz = __fmul_rn(mask[j], z2);
  float mu = __fmul_rn(mask[j], u2);
  out[n + j] = __fadd_rn(__fsub_rn(mz, mu), u2);
}
// FT scalar: r3 = (tA + tB) + c*u3 ; out = (r3 - u3) + u3
__global__ void k_r3FT(const float* scal, const float* u, float* out, int N) {
  if (threadIdx.x != 0 || blockIdx.x != 0) return;
  float u3 = u[N - 1];
  float r3 = __fadd_rn(__fadd_rn(scal[1], scal[2]), __fmul_rn(scal[0], u3));
  out[N - 1] = __fadd_rn(__fsub_rn(r3, u3), u3);
}

// ================= CG updates / epilogue =================
__global__ void k_upd1(float* zk, float* rk, const float* pk, const float* qk,
                       const float* gk, const float* qq, int N) {
  int i = blockIdx.x * BLK + threadIdx.x;
  if (i >= N) return;
  float alpha = __fdiv_rn(*gk, __fadd_rn(*qq, 1e-30f));
  zk[i] = __fadd_rn(zk[i], __fmul_rn(alpha, pk[i]));
  rk[i] = __fsub_rn(rk[i], __fmul_rn(alpha, qk[i]));
}
__global__ void k_upd2(float* pk, const float* sk, const float* gk, const float* gn, int N) {
  int i = blockIdx.x * BLK + threadIdx.x;
  if (i >= N) return;
  float beta = __fdiv_rn(*gn, __fadd_rn(*gk, 1e-30f));
  pk[i] = __fadd_rn(sk[i], __fmul_rn(beta, pk[i]));
}
__global__ void k_out(const float* zk, const float* x, const float* y, const float* s,
                      const float* mask, float* out, int n, int m, int N) {
  int i = blockIdx.x * BLK + threadIdx.x;
  float zN = zk[N - 1];
  if (i < n) out[i] = __fsub_rn(zk[i], __fmul_rn(x[i], zN));
  if (i < m) {
    float z2 = zk[n + i];
    float t = __fmul_rn(mask[i], z2);
    out[n + i] = __fsub_rn(t, __fmul_rn(y[i], zN));
    out[n + m + i] = __fsub_rn(__fsub_rn(t, z2), __fmul_rn(s[i], zN));
  }
}
__global__ void k_sentinel(float* out, int sz, float val) {
  int i = blockIdx.x * BLK + threadIdx.x;
  if (i < sz) out[i] = val;
}

extern "C" void kernel_launch(void* const* d_in, const int* in_sizes, int n_in,
                              void* d_out, int out_size, void* d_ws, size_t ws_size,
                              hipStream_t stream) {
  const float* Pd  = (const float*)d_in[0];
  const int*   Pr  = (const int*)d_in[1];
  const int*   Pc  = (const int*)d_in[2];
  const float* Ad  = (const float*)d_in[3];
  const int*   Ar  = (const int*)d_in[4];
  const int*   Ac  = (const int*)d_in[5];
  const float* q   = (const float*)d_in[6];
  const float* b   = (const float*)d_in[7];
  const float* x   = (const float*)d_in[8];
  const float* y   = (const float*)d_in[9];
  const float* s   = (const float*)d_in[10];
  const float* dPd = (const float*)d_in[11];
  const float* dAd = (const float*)d_in[12];
  const float* dq  = (const float*)d_in[13];
  const float* db  = (const float*)d_in[14];

  const int nnzP = in_sizes[0];
  const int nnzA = in_sizes[3];
  const int n = in_sizes[6];
  const int m = in_sizes[7];
  const int N = n + m + 1;
  float* out = (float*)d_out;
  const int gridOut = (out_size + BLK - 1) / BLK;

  size_t nInts = (size_t)3 * (n + 2) + (m + 2) + 2 * (size_t)nnzP + 2 * (size_t)nnzA
                 + ((m > n ? m : n) + 2) + 16;
  size_t nF32 = (size_t)3 * m + 3 * n + 4 * (size_t)N + 256;
  size_t needed = nInts * 4 + nF32 * 4;
  if (ws_size < needed) { k_sentinel<<<gridOut, BLK, 0, stream>>>(out, out_size, 165.0e6f); return; }

  int* ip = (int*)d_ws;
  int* ptrPr_ = ip;            ip += n + 2;
  int* ptrPc_ = ip;            ip += n + 2;
  int* ptrAr_ = ip;            ip += m + 2;
  int* ptrAc_ = ip;            ip += n + 2;
  int* permPr_ = ip;           ip += nnzP;
  int* permPc_ = ip;           ip += nnzP;
  int* permAr_ = ip;           ip += nnzA;
  int* permAc_ = ip;           ip += nnzA;
  int* cnt = ip;               ip += (m > n ? m : n) + 2;
  ip += 16;

  float* fp = (float*)ip;
  float* mask = fp;            fp += m;
  float* pim  = fp;            fp += m;
  float* w2   = fp;            fp += m;
  float* qg   = fp;            fp += n;
  float* Px   = fp;            fp += n;
  float* dPx  = fp;            fp += n;
  float* zk   = fp;            fp += N;
  float* rk   = fp;            fp += N;
  float* pk   = fp;            fp += N;
  float* qs   = fp;            fp += N;
  float* scal = fp;            fp += 256;

  const int gN  = (N + BLK - 1) / BLK;
  const int gn_ = (n + BLK - 1) / BLK;
  const int gm_ = (m + BLK - 1) / BLK;

  auto buildCSR = [&](const int* rows, int nnz, int segs, int* ptr, int* perm) {
    int len = segs + 1;
    int gSeg1 = (len + BLK - 1) / BLK;
    int gSeg  = (segs + BLK - 1) / BLK;
    int gNnz  = (nnz + BLK - 1) / BLK;
    k_zeroi<<<gSeg1, BLK, 0, stream>>>(cnt, len);
    k_hist<<<gNnz, BLK, 0, stream>>>(rows, nnz, cnt);
    k_scanA<<<gSeg1, BLK, 0, stream>>>(cnt, ptr, (int*)scal, segs, len);
    k_scanB<<<1, BLK, 0, stream>>>((int*)scal, gSeg1);
    k_scanC<<<gSeg1, BLK, 0, stream>>>(ptr, (const int*)scal, len);
    k_zeroi<<<gSeg1, BLK, 0, stream>>>(cnt, len);
    k_place<<<gNnz, BLK, 0, stream>>>(rows, nnz, ptr, cnt, perm);
    k_sortrows<<<gSeg, BLK, 0, stream>>>(perm, ptr, segs);
  };

  buildCSR(Pr, nnzP, n, ptrPr_, permPr_);
  buildCSR(Pc, nnzP, n, ptrPc_, permPc_);
  buildCSR(Ar, nnzA, m, ptrAr_, permAr_);
  buildCSR(Ac, nnzA, n, ptrAc_, permAc_);

  // setup: mask/pim ; Px ; qg ; c = x@Px  (scal zeroed by k_prep AFTER scan-scratch use)
  k_prep<<<gm_, BLK, 0, stream>>>(y, s, mask, pim, scal, m);
  k_Px<<<gn_, BLK, 0, stream>>>(ptrPr_, permPr_, Pd, Pc, x, Px, n);
  k_qg<<<gn_, BLK, 0, stream>>>(ptrPc_, permPc_, Pd, Pr, q, x, Px, qg, n);
  k_sdot<<<1, 32, 0, stream>>>(x, Px, n, scal + 0);   // c

  // rhs: d1, d2, d3 -> rk = -d, zk = 0
  k_dPx<<<gn_, BLK, 0, stream>>>(ptrPr_, permPr_, dPd, Pc, x, dPx, n);
  k_d1<<<gn_, BLK, 0, stream>>>(ptrAc_, permAc_, dAd, Ar, dPx, pim, dq, rk, zk, n);
  k_d2<<<gm_, BLK, 0, stream>>>(ptrAr_, permAr_, dAd, Ac, x, db, rk, zk, n, m);
  k_sdot<<<1, 32, 0, stream>>>(dq, x, n, scal + 1);   // dq@x
  k_sdot<<<1, 32, 0, stream>>>(db, pim, m, scal + 2); // db@pim
  k_sdot<<<1, 32, 0, stream>>>(x, dPx, n, scal + 3);  // x@dPx
  k_rhs3<<<1, 1, 0, stream>>>(scal, rk, zk, N);

  // s0 = FT(rhs) -> pk ; gk0 = s0@s0
  k_FTn<<<gn_, BLK, 0, stream>>>(ptrPc_, permPc_, Pd, Pr, ptrAc_, permAc_, Ad, Ar, qg, rk, pk, n, N);
  k_FTm<<<gm_, BLK, 0, stream>>>(ptrAr_, permAr_, Ad, Ac, b, mask, rk, pk, n, m, N);
  k_sdot<<<1, 32, 0, stream>>>(q, rk, n, scal + 1);       // q@u1
  k_sdot<<<1, 32, 0, stream>>>(b, rk + n, m, scal + 2);   // b@u2
  k_r3FT<<<1, 1, 0, stream>>>(scal, rk, pk, N);
  k_sdot<<<1, 32, 0, stream>>>(pk, pk, N, scal + 4);      // gk0

  for (int t = 0; t < NIT; ++t) {
    float* QQ = scal + 8 + 2 * t;
    float* GN = scal + 9 + 2 * t;
    float* GK = (t == 0) ? (scal + 4) : (scal + 9 + 2 * (t - 1));

    // qk = F(pk)
    k_w2<<<gm_, BLK, 0, stream>>>(pk, mask, w2, n, m);
    k_Fn<<<gn_, BLK, 0, stream>>>(ptrPr_, permPr_, Pd, Pc, ptrAc_, permAc_, Ad, Ar, q, mask, pk, qs, n, N);
    k_Fm<<<gm_, BLK, 0, stream>>>(ptrAr_, permAr_, Ad, Ac, b, mask, pk, qs, n, m, N);
    k_sdot<<<1, 32, 0, stream>>>(qg, pk, n, scal + 1);     // (q+g)@u1
    k_sdot<<<1, 32, 0, stream>>>(b, w2, m, scal + 2);      // b@w2
    k_r3F<<<1, 1, 0, stream>>>(scal, pk, qs, N);
    k_sdot<<<1, 32, 0, stream>>>(qs, qs, N, QQ);           // qk@qk
    k_upd1<<<gN, BLK, 0, stream>>>(zk, rk, pk, qs, GK, QQ, N);

    // sk = FT(rk)
    k_FTn<<<gn_, BLK, 0, stream>>>(ptrPc_, permPc_, Pd, Pr, ptrAc_, permAc_, Ad, Ar, qg, rk, qs, n, N);
    k_FTm<<<gm_, BLK, 0, stream>>>(ptrAr_, permAr_, Ad, Ac, b, mask, rk, qs, n, m, N);
    k_sdot<<<1, 32, 0, stream>>>(q, rk, n, scal + 1);
    k_sdot<<<1, 32, 0, stream>>>(b, rk + n, m, scal + 2);
    k_r3FT<<<1, 1, 0, stream>>>(scal, rk, qs, N);
    k_sdot<<<1, 32, 0, stream>>>(qs, qs, N, GN);           // sk@sk
    k_upd2<<<gN, BLK, 0, stream>>>(pk, qs, GK, GN, N);
  }

  k_out<<<gm_, BLK, 0, stream>>>(zk, x, y, s, mask, out, n, m, N);
}